// Round 4
// baseline (193.084 us; speedup 1.0000x reference)
//
#include <hip/hip_runtime.h>

#define N_SRC   100000
#define N_DST   50000
#define D       128
#define MAXDEG  64      // Poisson(12) row degree; P(deg>64) ~ 1e-30 for this data

typedef __attribute__((ext_vector_type(8))) short bf16x8;
typedef __attribute__((ext_vector_type(4))) float f32x4;

__device__ __forceinline__ unsigned short f2bf(float f) {
    unsigned u = __float_as_uint(f);
    u += 0x7FFFu + ((u >> 16) & 1u);   // RNE
    return (unsigned short)(u >> 16);
}
__device__ __forceinline__ float bf2f(unsigned short u) {
    return __uint_as_float((unsigned)u << 16);
}

// ---- fused prep+build: ELL scatter (latency) hidden under featconv (stream) ----
// cnt must be zeroed by a preceding memset. Edge atomics issued first so their
// latency overlaps the grid-stride fp32->bf16 streaming conversion.
__global__ __launch_bounds__(256)
void prep_build_kernel(const int* __restrict__ src,
                       const int* __restrict__ dst,
                       int* __restrict__ ell,
                       int* __restrict__ cnt,
                       int n_edges,
                       const int* __restrict__ reuse_idx,
                       int* __restrict__ rowpos, int n_reuse,
                       const float* __restrict__ Wself,
                       const float* __restrict__ Wneigh,
                       unsigned short* __restrict__ wbf,
                       const float* __restrict__ feat,
                       unsigned int* __restrict__ featbf_u32) {
    int tid = blockIdx.x * blockDim.x + threadIdx.x;
    int stride = gridDim.x * blockDim.x;

    // 1) ELL build (grid-stride over edges; ~1.15 iter/thread at 2048x256)
    for (int e = tid; e < n_edges; e += stride) {
        int d = dst[e];
        int pos = atomicAdd(&cnt[d], 1);
        if (pos < MAXDEG)
            ell[(size_t)d * MAXDEG + pos] = src[e];
    }

    // 2) rowpos binary search
    if (tid < N_DST) {
        int lo = 0, hi = n_reuse;
        while (lo < hi) {
            int mid = (lo + hi) >> 1;
            if (reuse_idx[mid] - mid > tid) hi = mid; else lo = mid + 1;
        }
        rowpos[tid] = tid + lo;
    }

    // 3) W -> bf16 combined [n][256] = [Wself | Wneigh]
    if (tid < 128 * 256) {
        int n = tid >> 8;
        int k = tid & 255;
        float v = (k < 128) ? Wself[n * 128 + k] : Wneigh[n * 128 + (k - 128)];
        wbf[tid] = f2bf(v);
    }

    // 4) feat fp32 -> bf16 (the BW bulk: 51.2 MB read + 25.6 MB write)
    const int n4 = N_SRC * (D / 4);
    for (int i = tid; i < n4; i += stride) {
        float4 v = *(const float4*)(feat + (size_t)i * 4);
        uint2 o;
        o.x = (unsigned)f2bf(v.x) | ((unsigned)f2bf(v.y) << 16);
        o.y = (unsigned)f2bf(v.z) | ((unsigned)f2bf(v.w) << 16);
        *(uint2*)(featbf_u32 + (size_t)i * 2) = o;
    }
}

// ---------------- pull-gather from bf16 feat -> bf16 hneigh ----------------
// 16 lanes per row, 16 B/lane (8 bf16) loads: 256 B per edge.
__global__ __launch_bounds__(256)
void gather_bf16_kernel(const unsigned short* __restrict__ featbf,
                        const int* __restrict__ ell,
                        const int* __restrict__ cnt,
                        uint4* __restrict__ hneigh_u4) {
    int gid  = blockIdx.x * blockDim.x + threadIdx.x;
    int row  = gid >> 4;
    int lane = gid & 15;
    if (row >= N_DST) return;

    int deg = cnt[row];
    int n = min(deg, MAXDEG);
    float inv = 1.0f / fmaxf((float)deg, 1.0f);
    const int* rell = ell + (size_t)row * MAXDEG;

    float acc[8];
#pragma unroll
    for (int k = 0; k < 8; ++k) acc[k] = 0.f;

    union U { uint4 v; unsigned short us[8]; };
    int j = 0;
    for (; j + 4 <= n; j += 4) {
        int s0 = rell[j + 0];
        int s1 = rell[j + 1];
        int s2 = rell[j + 2];
        int s3 = rell[j + 3];
        U a, b, c, d;
        a.v = *(const uint4*)(featbf + (size_t)s0 * D + lane * 8);
        b.v = *(const uint4*)(featbf + (size_t)s1 * D + lane * 8);
        c.v = *(const uint4*)(featbf + (size_t)s2 * D + lane * 8);
        d.v = *(const uint4*)(featbf + (size_t)s3 * D + lane * 8);
#pragma unroll
        for (int k = 0; k < 8; ++k)
            acc[k] += (bf2f(a.us[k]) + bf2f(b.us[k])) + (bf2f(c.us[k]) + bf2f(d.us[k]));
    }
    for (; j < n; ++j) {
        int s = rell[j];
        U a;
        a.v = *(const uint4*)(featbf + (size_t)s * D + lane * 8);
#pragma unroll
        for (int k = 0; k < 8; ++k) acc[k] += bf2f(a.us[k]);
    }
    uint4 o;
    o.x = (unsigned)f2bf(acc[0] * inv) | ((unsigned)f2bf(acc[1] * inv) << 16);
    o.y = (unsigned)f2bf(acc[2] * inv) | ((unsigned)f2bf(acc[3] * inv) << 16);
    o.z = (unsigned)f2bf(acc[4] * inv) | ((unsigned)f2bf(acc[5] * inv) << 16);
    o.w = (unsigned)f2bf(acc[6] * inv) | ((unsigned)f2bf(acc[7] * inv) << 16);
    hneigh_u4[(size_t)row * 16 + lane] = o;
}

// ---- bf16 MFMA GEMM (fast path): A entirely bf16 (featbf | hneigh) ----
// W staged once in LDS (XOR chunk-swizzle); K-loop has NO barriers.
__global__ __launch_bounds__(256, 2)
void gemm_kernel(const unsigned short* __restrict__ featbf,   // bf16 bits [N_SRC][128]
                 const unsigned short* __restrict__ hneigh,   // bf16 bits [N_DST][128]
                 const unsigned short* __restrict__ wbf,      // bf16 bits [128][256]
                 const int* __restrict__ rowpos,
                 float* __restrict__ full) {
    __shared__ unsigned short Wl[128 * 256];   // 64 KiB; chunk c of row n at c^(n&7)

    int tid = threadIdx.x;
    {   // stage W: 16-B chunks, swizzled
        int n = tid >> 1;
        int ckbase = (tid & 1) * 16;
        const uint4* s = (const uint4*)(wbf + n * 256);
        uint4* d = (uint4*)(Wl + n * 256);
#pragma unroll
        for (int i = 0; i < 16; ++i) {
            int ck = ckbase + i;
            d[ck ^ (n & 7)] = s[ck];
        }
    }
    __syncthreads();

    int wv   = tid >> 6;
    int lane = tid & 63;
    int l15  = lane & 15;
    int q    = lane >> 4;
    int rowbase = blockIdx.x * 128 + wv * 32;

    f32x4 acc[2][8];
#pragma unroll
    for (int rt = 0; rt < 2; ++rt)
#pragma unroll
        for (int ct = 0; ct < 8; ++ct) acc[rt][ct] = (f32x4){0.f, 0.f, 0.f, 0.f};

    int r0c = min(rowbase + l15,      N_DST - 1);
    int r1c = min(rowbase + 16 + l15, N_DST - 1);

    // k = 0..255: s<4 from featbf (bit-identical to in-reg f2bf of feat), s>=4 hneigh
#pragma unroll
    for (int s = 0; s < 8; ++s) {
        const unsigned short* A = (s < 4) ? featbf : hneigh;
        int k0 = (s & 3) * 32 + q * 8;
        bf16x8 a0 = *(const bf16x8*)(A + (size_t)r0c * D + k0);
        bf16x8 a1 = *(const bf16x8*)(A + (size_t)r1c * D + k0);
#pragma unroll
        for (int ct = 0; ct < 8; ++ct) {
            int n = ct * 16 + l15;
            int ck = s * 4 + q;
            bf16x8 b = *(const bf16x8*)(Wl + n * 256 + ((ck ^ (n & 7)) << 3));
            acc[0][ct] = __builtin_amdgcn_mfma_f32_16x16x32_bf16(a0, b, acc[0][ct], 0, 0, 0);
            acc[1][ct] = __builtin_amdgcn_mfma_f32_16x16x32_bf16(a1, b, acc[1][ct], 0, 0, 0);
        }
    }

    // epilogue: C/D layout col=l15, row=q*4+reg; scatter rows via rowpos
#pragma unroll
    for (int rt = 0; rt < 2; ++rt) {
#pragma unroll
        for (int reg = 0; reg < 4; ++reg) {
            int gm = rowbase + rt * 16 + q * 4 + reg;
            if (gm < N_DST) {
                int jj = rowpos[gm];
                float* outr = full + (size_t)jj * D + l15;
#pragma unroll
                for (int ct = 0; ct < 8; ++ct)
                    outr[ct * 16] = acc[rt][ct][reg];
            }
        }
    }
}

// ---- fallback GEMM (r2-verified): phase-1 A from fp32 feat ----
__global__ __launch_bounds__(256, 2)
void gemm_f32a_kernel(const float* __restrict__ feat,
                      const unsigned short* __restrict__ hneigh,
                      const unsigned short* __restrict__ wbf,
                      const int* __restrict__ rowpos,
                      float* __restrict__ full) {
    __shared__ unsigned short Wl[128 * 256];

    int tid = threadIdx.x;
    {
        int n = tid >> 1;
        int ckbase = (tid & 1) * 16;
        const uint4* s = (const uint4*)(wbf + n * 256);
        uint4* d = (uint4*)(Wl + n * 256);
#pragma unroll
        for (int i = 0; i < 16; ++i) {
            int ck = ckbase + i;
            d[ck ^ (n & 7)] = s[ck];
        }
    }
    __syncthreads();

    int wv   = tid >> 6;
    int lane = tid & 63;
    int l15  = lane & 15;
    int q    = lane >> 4;
    int rowbase = blockIdx.x * 128 + wv * 32;

    f32x4 acc[2][8];
#pragma unroll
    for (int rt = 0; rt < 2; ++rt)
#pragma unroll
        for (int ct = 0; ct < 8; ++ct) acc[rt][ct] = (f32x4){0.f, 0.f, 0.f, 0.f};

    int r0c = min(rowbase + l15,      N_DST - 1);
    int r1c = min(rowbase + 16 + l15, N_DST - 1);

#pragma unroll 1
    for (int s = 0; s < 4; ++s) {
        int k0 = s * 32 + q * 8;
        float4 a0lo = *(const float4*)(feat + (size_t)r0c * D + k0);
        float4 a0hi = *(const float4*)(feat + (size_t)r0c * D + k0 + 4);
        float4 a1lo = *(const float4*)(feat + (size_t)r1c * D + k0);
        float4 a1hi = *(const float4*)(feat + (size_t)r1c * D + k0 + 4);
        union { bf16x8 v; unsigned short u[8]; } a0, a1;
        a0.u[0] = f2bf(a0lo.x); a0.u[1] = f2bf(a0lo.y);
        a0.u[2] = f2bf(a0lo.z); a0.u[3] = f2bf(a0lo.w);
        a0.u[4] = f2bf(a0hi.x); a0.u[5] = f2bf(a0hi.y);
        a0.u[6] = f2bf(a0hi.z); a0.u[7] = f2bf(a0hi.w);
        a1.u[0] = f2bf(a1lo.x); a1.u[1] = f2bf(a1lo.y);
        a1.u[2] = f2bf(a1lo.z); a1.u[3] = f2bf(a1lo.w);
        a1.u[4] = f2bf(a1hi.x); a1.u[5] = f2bf(a1hi.y);
        a1.u[6] = f2bf(a1hi.z); a1.u[7] = f2bf(a1hi.w);
#pragma unroll
        for (int ct = 0; ct < 8; ++ct) {
            int n = ct * 16 + l15;
            int ck = s * 4 + q;
            bf16x8 b = *(const bf16x8*)(Wl + n * 256 + ((ck ^ (n & 7)) << 3));
            acc[0][ct] = __builtin_amdgcn_mfma_f32_16x16x32_bf16(a0.v, b, acc[0][ct], 0, 0, 0);
            acc[1][ct] = __builtin_amdgcn_mfma_f32_16x16x32_bf16(a1.v, b, acc[1][ct], 0, 0, 0);
        }
    }
#pragma unroll 1
    for (int s = 0; s < 4; ++s) {
        int k0 = s * 32 + q * 8;
        bf16x8 a0 = *(const bf16x8*)(hneigh + (size_t)r0c * D + k0);
        bf16x8 a1 = *(const bf16x8*)(hneigh + (size_t)r1c * D + k0);
#pragma unroll
        for (int ct = 0; ct < 8; ++ct) {
            int n = ct * 16 + l15;
            int ck = 16 + s * 4 + q;
            bf16x8 b = *(const bf16x8*)(Wl + n * 256 + ((ck ^ (n & 7)) << 3));
            acc[0][ct] = __builtin_amdgcn_mfma_f32_16x16x32_bf16(a0, b, acc[0][ct], 0, 0, 0);
            acc[1][ct] = __builtin_amdgcn_mfma_f32_16x16x32_bf16(a1, b, acc[1][ct], 0, 0, 0);
        }
    }

#pragma unroll
    for (int rt = 0; rt < 2; ++rt) {
#pragma unroll
        for (int reg = 0; reg < 4; ++reg) {
            int gm = rowbase + rt * 16 + q * 4 + reg;
            if (gm < N_DST) {
                int jj = rowpos[gm];
                float* outr = full + (size_t)jj * D + l15;
#pragma unroll
                for (int ct = 0; ct < 8; ++ct)
                    outr[ct * 16] = acc[rt][ct][reg];
            }
        }
    }
}

// ---- fused epilogue: reuse rows into full + cache gather (reuse-aware) ----
// cache rows that hit a reuse index read emb directly (bit-identical), so no
// ordering dependence on the reuse writes within this kernel.
__global__ __launch_bounds__(256)
void epilogue_kernel(const float* __restrict__ emb,
                     const int* __restrict__ ridx, int n_reuse,
                     float* __restrict__ full,
                     const int* __restrict__ cidx,
                     float* __restrict__ cache_out, int n_cache) {
    int idx = blockIdx.x * blockDim.x + threadIdx.x;
    int row = idx >> 5;
    int c4 = (idx & 31) * 4;
    if (row < n_reuse) {
        *(float4*)&full[(size_t)ridx[row] * D + c4] =
            *(const float4*)&emb[(size_t)row * D + c4];
    } else if (row < n_reuse + n_cache) {
        int r = row - n_reuse;
        int v = cidx[r];
        int lo = 0, hi = n_reuse;
        while (lo < hi) {
            int mid = (lo + hi) >> 1;
            if (ridx[mid] < v) lo = mid + 1; else hi = mid;
        }
        const float* srcp = (lo < n_reuse && ridx[lo] == v)
            ? emb + (size_t)lo * D
            : full + (size_t)v * D;
        *(float4*)&cache_out[(size_t)r * D + c4] = *(const float4*)&srcp[c4];
    }
}

extern "C" void kernel_launch(void* const* d_in, const int* in_sizes, int n_in,
                              void* d_out, int out_size, void* d_ws, size_t ws_size,
                              hipStream_t stream) {
    const float* feat_src  = (const float*)d_in[0];
    const float* W_self    = (const float*)d_in[1];
    const float* W_neigh   = (const float*)d_in[2];
    const float* reuse_emb = (const float*)d_in[3];
    const int*   src       = (const int*)d_in[4];
    const int*   dst       = (const int*)d_in[5];
    const int*   reuse_idx = (const int*)d_in[6];
    const int*   cache_idx = (const int*)d_in[7];

    int n_edges = in_sizes[4];
    int n_reuse = in_sizes[6];
    int n_cache = in_sizes[7];
    int full_len = N_DST + n_reuse;

    float* full = (float*)d_out;                      // 55000*128 fp32
    float* cache_out = full + (size_t)full_len * D;   // 8000*128

    size_t hneigh_b = (size_t)N_DST * D * sizeof(unsigned short);   // 12.8 MB
    size_t featbf_b = (size_t)N_SRC * D * sizeof(unsigned short);   // 25.6 MB
    size_t ell_b    = (size_t)N_DST * MAXDEG * sizeof(int);         // 12.8 MB
    size_t small_b  = 2 * (size_t)N_DST * 4 + 128 * 256 * 2;
    size_t need_fast = hneigh_b + featbf_b + small_b;               // ~38.9 MB

    int ep_rows = n_reuse + n_cache;

    if (ws_size >= need_fast) {
        // ---- fast path ----
        // ws: hneigh | featbf | cnt | rowpos | wbf.  ELL (12.8 MB) borrows d_out's
        // `full` region: consumed by gather before gemm overwrites it.
        unsigned short* hneigh = (unsigned short*)d_ws;
        unsigned short* featbf = (unsigned short*)((char*)d_ws + hneigh_b);
        int*   cnt    = (int*)((char*)featbf + featbf_b);
        int*   rowpos = cnt + N_DST;
        unsigned short* wbf = (unsigned short*)(rowpos + N_DST);
        int* ell = (int*)full;

        hipMemsetAsync(cnt, 0, (size_t)N_DST * sizeof(int), stream);

        prep_build_kernel<<<2048, 256, 0, stream>>>(
            src, dst, ell, cnt, n_edges,
            reuse_idx, rowpos, n_reuse, W_self, W_neigh, wbf,
            feat_src, (unsigned int*)featbf);

        gather_bf16_kernel<<<(N_DST * 16 + 255) / 256, 256, 0, stream>>>(
            featbf, ell, cnt, (uint4*)hneigh);

        gemm_kernel<<<(N_DST + 127) / 128, 256, 0, stream>>>(
            featbf, hneigh, wbf, rowpos, full);

        epilogue_kernel<<<(ep_rows * 32 + 255) / 256, 256, 0, stream>>>(
            reuse_emb, reuse_idx, n_reuse, full, cache_idx, cache_out, n_cache);
    } else {
        // ---- fallback (r2-verified layout): ell in ws, featbf borrows d_out ----
        unsigned short* hneigh = (unsigned short*)d_ws;
        int*   ell    = (int*)((char*)d_ws + hneigh_b);
        int*   cnt    = (int*)((char*)ell + ell_b);
        int*   rowpos = cnt + N_DST;
        unsigned short* wbf = (unsigned short*)(rowpos + N_DST);
        unsigned short* featbf = (unsigned short*)full;

        hipMemsetAsync(cnt, 0, (size_t)N_DST * sizeof(int), stream);

        prep_build_kernel<<<2048, 256, 0, stream>>>(
            src, dst, ell, cnt, n_edges,
            reuse_idx, rowpos, n_reuse, W_self, W_neigh, wbf,
            feat_src, (unsigned int*)featbf);

        gather_bf16_kernel<<<(N_DST * 16 + 255) / 256, 256, 0, stream>>>(
            featbf, ell, cnt, (uint4*)hneigh);

        gemm_f32a_kernel<<<(N_DST + 127) / 128, 256, 0, stream>>>(
            feat_src, hneigh, wbf, rowpos, full);

        epilogue_kernel<<<(ep_rows * 32 + 255) / 256, 256, 0, stream>>>(
            reuse_emb, reuse_idx, n_reuse, full, cache_idx, cache_out, n_cache);
    }
}

// Round 5
// 185.990 us; speedup vs baseline: 1.0381x; 1.0381x over previous
//
#include <hip/hip_runtime.h>

#define N_SRC   100000
#define N_DST   50000
#define D       128
#define MAXDEG  64      // Poisson(12) row degree; P(deg>64) ~ 1e-30 for this data

#define TOTAL_BLOCKS 2048
#define EDGE_BLOCKS  512    // blocks 0..511: ELL scatter; rest: streaming prep

typedef __attribute__((ext_vector_type(8))) short bf16x8;
typedef __attribute__((ext_vector_type(4))) float f32x4;

__device__ __forceinline__ unsigned short f2bf(float f) {
    unsigned u = __float_as_uint(f);
    u += 0x7FFFu + ((u >> 16) & 1u);   // RNE
    return (unsigned short)(u >> 16);
}
__device__ __forceinline__ float bf2f(unsigned short u) {
    return __uint_as_float((unsigned)u << 16);
}

// ---- block-partitioned prep+build: edge blocks and stream blocks co-resident ----
// Blocks [0, EDGE_BLOCKS): ELL scatter (atomic-throughput-bound, few CUs needed).
// Blocks [EDGE_BLOCKS, TOTAL): rowpos + wconv + feat fp32->bf16 (BW-bound).
// Low VGPR count => all 2048 blocks resident (8/CU) => true concurrency.
// cnt must be zeroed by a preceding memset.
__global__ __launch_bounds__(256)
void prep_build_kernel(const int* __restrict__ src,
                       const int* __restrict__ dst,
                       int* __restrict__ ell,
                       int* __restrict__ cnt,
                       int n_edges,
                       const int* __restrict__ reuse_idx,
                       int* __restrict__ rowpos, int n_reuse,
                       const float* __restrict__ Wself,
                       const float* __restrict__ Wneigh,
                       unsigned short* __restrict__ wbf,
                       const float* __restrict__ feat,
                       unsigned int* __restrict__ featbf_u32) {
    if (blockIdx.x < EDGE_BLOCKS) {
        // ---- edge scatter ----
        int eid = blockIdx.x * 256 + threadIdx.x;
        const int estride = EDGE_BLOCKS * 256;
        for (int e = eid; e < n_edges; e += estride) {
            int d = dst[e];
            int pos = atomicAdd(&cnt[d], 1);
            if (pos < MAXDEG)
                ell[(size_t)d * MAXDEG + pos] = src[e];
        }
    } else {
        int stid = (blockIdx.x - EDGE_BLOCKS) * 256 + threadIdx.x;
        const int sstride = (TOTAL_BLOCKS - EDGE_BLOCKS) * 256;

        // rowpos binary search
        if (stid < N_DST) {
            int lo = 0, hi = n_reuse;
            while (lo < hi) {
                int mid = (lo + hi) >> 1;
                if (reuse_idx[mid] - mid > stid) hi = mid; else lo = mid + 1;
            }
            rowpos[stid] = stid + lo;
        }

        // W -> bf16 combined [n][256] = [Wself | Wneigh]
        if (stid < 128 * 256) {
            int n = stid >> 8;
            int k = stid & 255;
            float v = (k < 128) ? Wself[n * 128 + k] : Wneigh[n * 128 + (k - 128)];
            wbf[stid] = f2bf(v);
        }

        // feat fp32 -> bf16 (the BW bulk: 51.2 MB read + 25.6 MB write)
        const int n4 = N_SRC * (D / 4);
        for (int i = stid; i < n4; i += sstride) {
            float4 v = *(const float4*)(feat + (size_t)i * 4);
            uint2 o;
            o.x = (unsigned)f2bf(v.x) | ((unsigned)f2bf(v.y) << 16);
            o.y = (unsigned)f2bf(v.z) | ((unsigned)f2bf(v.w) << 16);
            *(uint2*)(featbf_u32 + (size_t)i * 2) = o;
        }
    }
}

// ---------------- pull-gather from bf16 feat -> bf16 hneigh ----------------
// 16 lanes per row, 16 B/lane (8 bf16) loads: 256 B per edge.
__global__ __launch_bounds__(256)
void gather_bf16_kernel(const unsigned short* __restrict__ featbf,
                        const int* __restrict__ ell,
                        const int* __restrict__ cnt,
                        uint4* __restrict__ hneigh_u4) {
    int gid  = blockIdx.x * blockDim.x + threadIdx.x;
    int row  = gid >> 4;
    int lane = gid & 15;
    if (row >= N_DST) return;

    int deg = cnt[row];
    int n = min(deg, MAXDEG);
    float inv = 1.0f / fmaxf((float)deg, 1.0f);
    const int* rell = ell + (size_t)row * MAXDEG;

    float acc[8];
#pragma unroll
    for (int k = 0; k < 8; ++k) acc[k] = 0.f;

    union U { uint4 v; unsigned short us[8]; };
    int j = 0;
    for (; j + 4 <= n; j += 4) {
        int s0 = rell[j + 0];
        int s1 = rell[j + 1];
        int s2 = rell[j + 2];
        int s3 = rell[j + 3];
        U a, b, c, d;
        a.v = *(const uint4*)(featbf + (size_t)s0 * D + lane * 8);
        b.v = *(const uint4*)(featbf + (size_t)s1 * D + lane * 8);
        c.v = *(const uint4*)(featbf + (size_t)s2 * D + lane * 8);
        d.v = *(const uint4*)(featbf + (size_t)s3 * D + lane * 8);
#pragma unroll
        for (int k = 0; k < 8; ++k)
            acc[k] += (bf2f(a.us[k]) + bf2f(b.us[k])) + (bf2f(c.us[k]) + bf2f(d.us[k]));
    }
    for (; j < n; ++j) {
        int s = rell[j];
        U a;
        a.v = *(const uint4*)(featbf + (size_t)s * D + lane * 8);
#pragma unroll
        for (int k = 0; k < 8; ++k) acc[k] += bf2f(a.us[k]);
    }
    uint4 o;
    o.x = (unsigned)f2bf(acc[0] * inv) | ((unsigned)f2bf(acc[1] * inv) << 16);
    o.y = (unsigned)f2bf(acc[2] * inv) | ((unsigned)f2bf(acc[3] * inv) << 16);
    o.z = (unsigned)f2bf(acc[4] * inv) | ((unsigned)f2bf(acc[5] * inv) << 16);
    o.w = (unsigned)f2bf(acc[6] * inv) | ((unsigned)f2bf(acc[7] * inv) << 16);
    hneigh_u4[(size_t)row * 16 + lane] = o;
}

// ---- bf16 MFMA GEMM (fast path): A entirely bf16 (featbf | hneigh) ----
// W staged once in LDS (XOR chunk-swizzle); K-loop has NO barriers.
__global__ __launch_bounds__(256, 2)
void gemm_kernel(const unsigned short* __restrict__ featbf,   // bf16 bits [N_SRC][128]
                 const unsigned short* __restrict__ hneigh,   // bf16 bits [N_DST][128]
                 const unsigned short* __restrict__ wbf,      // bf16 bits [128][256]
                 const int* __restrict__ rowpos,
                 float* __restrict__ full) {
    __shared__ unsigned short Wl[128 * 256];   // 64 KiB; chunk c of row n at c^(n&7)

    int tid = threadIdx.x;
    {   // stage W: 16-B chunks, swizzled
        int n = tid >> 1;
        int ckbase = (tid & 1) * 16;
        const uint4* s = (const uint4*)(wbf + n * 256);
        uint4* d = (uint4*)(Wl + n * 256);
#pragma unroll
        for (int i = 0; i < 16; ++i) {
            int ck = ckbase + i;
            d[ck ^ (n & 7)] = s[ck];
        }
    }
    __syncthreads();

    int wv   = tid >> 6;
    int lane = tid & 63;
    int l15  = lane & 15;
    int q    = lane >> 4;
    int rowbase = blockIdx.x * 128 + wv * 32;

    f32x4 acc[2][8];
#pragma unroll
    for (int rt = 0; rt < 2; ++rt)
#pragma unroll
        for (int ct = 0; ct < 8; ++ct) acc[rt][ct] = (f32x4){0.f, 0.f, 0.f, 0.f};

    int r0c = min(rowbase + l15,      N_DST - 1);
    int r1c = min(rowbase + 16 + l15, N_DST - 1);

    // k = 0..255: s<4 from featbf (bit-identical to in-reg f2bf of feat), s>=4 hneigh
#pragma unroll
    for (int s = 0; s < 8; ++s) {
        const unsigned short* A = (s < 4) ? featbf : hneigh;
        int k0 = (s & 3) * 32 + q * 8;
        bf16x8 a0 = *(const bf16x8*)(A + (size_t)r0c * D + k0);
        bf16x8 a1 = *(const bf16x8*)(A + (size_t)r1c * D + k0);
#pragma unroll
        for (int ct = 0; ct < 8; ++ct) {
            int n = ct * 16 + l15;
            int ck = s * 4 + q;
            bf16x8 b = *(const bf16x8*)(Wl + n * 256 + ((ck ^ (n & 7)) << 3));
            acc[0][ct] = __builtin_amdgcn_mfma_f32_16x16x32_bf16(a0, b, acc[0][ct], 0, 0, 0);
            acc[1][ct] = __builtin_amdgcn_mfma_f32_16x16x32_bf16(a1, b, acc[1][ct], 0, 0, 0);
        }
    }

    // epilogue: C/D layout col=l15, row=q*4+reg; scatter rows via rowpos
#pragma unroll
    for (int rt = 0; rt < 2; ++rt) {
#pragma unroll
        for (int reg = 0; reg < 4; ++reg) {
            int gm = rowbase + rt * 16 + q * 4 + reg;
            if (gm < N_DST) {
                int jj = rowpos[gm];
                float* outr = full + (size_t)jj * D + l15;
#pragma unroll
                for (int ct = 0; ct < 8; ++ct)
                    outr[ct * 16] = acc[rt][ct][reg];
            }
        }
    }
}

// ---- fallback GEMM (r2-verified): phase-1 A from fp32 feat ----
__global__ __launch_bounds__(256, 2)
void gemm_f32a_kernel(const float* __restrict__ feat,
                      const unsigned short* __restrict__ hneigh,
                      const unsigned short* __restrict__ wbf,
                      const int* __restrict__ rowpos,
                      float* __restrict__ full) {
    __shared__ unsigned short Wl[128 * 256];

    int tid = threadIdx.x;
    {
        int n = tid >> 1;
        int ckbase = (tid & 1) * 16;
        const uint4* s = (const uint4*)(wbf + n * 256);
        uint4* d = (uint4*)(Wl + n * 256);
#pragma unroll
        for (int i = 0; i < 16; ++i) {
            int ck = ckbase + i;
            d[ck ^ (n & 7)] = s[ck];
        }
    }
    __syncthreads();

    int wv   = tid >> 6;
    int lane = tid & 63;
    int l15  = lane & 15;
    int q    = lane >> 4;
    int rowbase = blockIdx.x * 128 + wv * 32;

    f32x4 acc[2][8];
#pragma unroll
    for (int rt = 0; rt < 2; ++rt)
#pragma unroll
        for (int ct = 0; ct < 8; ++ct) acc[rt][ct] = (f32x4){0.f, 0.f, 0.f, 0.f};

    int r0c = min(rowbase + l15,      N_DST - 1);
    int r1c = min(rowbase + 16 + l15, N_DST - 1);

#pragma unroll 1
    for (int s = 0; s < 4; ++s) {
        int k0 = s * 32 + q * 8;
        float4 a0lo = *(const float4*)(feat + (size_t)r0c * D + k0);
        float4 a0hi = *(const float4*)(feat + (size_t)r0c * D + k0 + 4);
        float4 a1lo = *(const float4*)(feat + (size_t)r1c * D + k0);
        float4 a1hi = *(const float4*)(feat + (size_t)r1c * D + k0 + 4);
        union { bf16x8 v; unsigned short u[8]; } a0, a1;
        a0.u[0] = f2bf(a0lo.x); a0.u[1] = f2bf(a0lo.y);
        a0.u[2] = f2bf(a0lo.z); a0.u[3] = f2bf(a0lo.w);
        a0.u[4] = f2bf(a0hi.x); a0.u[5] = f2bf(a0hi.y);
        a0.u[6] = f2bf(a0hi.z); a0.u[7] = f2bf(a0hi.w);
        a1.u[0] = f2bf(a1lo.x); a1.u[1] = f2bf(a1lo.y);
        a1.u[2] = f2bf(a1lo.z); a1.u[3] = f2bf(a1lo.w);
        a1.u[4] = f2bf(a1hi.x); a1.u[5] = f2bf(a1hi.y);
        a1.u[6] = f2bf(a1hi.z); a1.u[7] = f2bf(a1hi.w);
#pragma unroll
        for (int ct = 0; ct < 8; ++ct) {
            int n = ct * 16 + l15;
            int ck = s * 4 + q;
            bf16x8 b = *(const bf16x8*)(Wl + n * 256 + ((ck ^ (n & 7)) << 3));
            acc[0][ct] = __builtin_amdgcn_mfma_f32_16x16x32_bf16(a0.v, b, acc[0][ct], 0, 0, 0);
            acc[1][ct] = __builtin_amdgcn_mfma_f32_16x16x32_bf16(a1.v, b, acc[1][ct], 0, 0, 0);
        }
    }
#pragma unroll 1
    for (int s = 0; s < 4; ++s) {
        int k0 = s * 32 + q * 8;
        bf16x8 a0 = *(const bf16x8*)(hneigh + (size_t)r0c * D + k0);
        bf16x8 a1 = *(const bf16x8*)(hneigh + (size_t)r1c * D + k0);
#pragma unroll
        for (int ct = 0; ct < 8; ++ct) {
            int n = ct * 16 + l15;
            int ck = 16 + s * 4 + q;
            bf16x8 b = *(const bf16x8*)(Wl + n * 256 + ((ck ^ (n & 7)) << 3));
            acc[0][ct] = __builtin_amdgcn_mfma_f32_16x16x32_bf16(a0, b, acc[0][ct], 0, 0, 0);
            acc[1][ct] = __builtin_amdgcn_mfma_f32_16x16x32_bf16(a1, b, acc[1][ct], 0, 0, 0);
        }
    }

#pragma unroll
    for (int rt = 0; rt < 2; ++rt) {
#pragma unroll
        for (int reg = 0; reg < 4; ++reg) {
            int gm = rowbase + rt * 16 + q * 4 + reg;
            if (gm < N_DST) {
                int jj = rowpos[gm];
                float* outr = full + (size_t)jj * D + l15;
#pragma unroll
                for (int ct = 0; ct < 8; ++ct)
                    outr[ct * 16] = acc[rt][ct][reg];
            }
        }
    }
}

// ---- fused epilogue: reuse rows into full + cache gather (reuse-aware) ----
// cache rows that hit a reuse index read emb directly (bit-identical), so no
// ordering dependence on the reuse writes within this kernel.
__global__ __launch_bounds__(256)
void epilogue_kernel(const float* __restrict__ emb,
                     const int* __restrict__ ridx, int n_reuse,
                     float* __restrict__ full,
                     const int* __restrict__ cidx,
                     float* __restrict__ cache_out, int n_cache) {
    int idx = blockIdx.x * blockDim.x + threadIdx.x;
    int row = idx >> 5;
    int c4 = (idx & 31) * 4;
    if (row < n_reuse) {
        *(float4*)&full[(size_t)ridx[row] * D + c4] =
            *(const float4*)&emb[(size_t)row * D + c4];
    } else if (row < n_reuse + n_cache) {
        int r = row - n_reuse;
        int v = cidx[r];
        int lo = 0, hi = n_reuse;
        while (lo < hi) {
            int mid = (lo + hi) >> 1;
            if (ridx[mid] < v) lo = mid + 1; else hi = mid;
        }
        const float* srcp = (lo < n_reuse && ridx[lo] == v)
            ? emb + (size_t)lo * D
            : full + (size_t)v * D;
        *(float4*)&cache_out[(size_t)r * D + c4] = *(const float4*)&srcp[c4];
    }
}

extern "C" void kernel_launch(void* const* d_in, const int* in_sizes, int n_in,
                              void* d_out, int out_size, void* d_ws, size_t ws_size,
                              hipStream_t stream) {
    const float* feat_src  = (const float*)d_in[0];
    const float* W_self    = (const float*)d_in[1];
    const float* W_neigh   = (const float*)d_in[2];
    const float* reuse_emb = (const float*)d_in[3];
    const int*   src       = (const int*)d_in[4];
    const int*   dst       = (const int*)d_in[5];
    const int*   reuse_idx = (const int*)d_in[6];
    const int*   cache_idx = (const int*)d_in[7];

    int n_edges = in_sizes[4];
    int n_reuse = in_sizes[6];
    int n_cache = in_sizes[7];
    int full_len = N_DST + n_reuse;

    float* full = (float*)d_out;                      // 55000*128 fp32
    float* cache_out = full + (size_t)full_len * D;   // 8000*128

    size_t hneigh_b = (size_t)N_DST * D * sizeof(unsigned short);   // 12.8 MB
    size_t featbf_b = (size_t)N_SRC * D * sizeof(unsigned short);   // 25.6 MB
    size_t ell_b    = (size_t)N_DST * MAXDEG * sizeof(int);         // 12.8 MB
    size_t small_b  = 2 * (size_t)N_DST * 4 + 128 * 256 * 2;
    size_t need_fast = hneigh_b + featbf_b + small_b;               // ~38.9 MB

    int ep_rows = n_reuse + n_cache;

    if (ws_size >= need_fast) {
        // ---- fast path ----
        // ws: hneigh | featbf | cnt | rowpos | wbf.  ELL (12.8 MB) borrows d_out's
        // `full` region: consumed by gather before gemm overwrites it.
        unsigned short* hneigh = (unsigned short*)d_ws;
        unsigned short* featbf = (unsigned short*)((char*)d_ws + hneigh_b);
        int*   cnt    = (int*)((char*)featbf + featbf_b);
        int*   rowpos = cnt + N_DST;
        unsigned short* wbf = (unsigned short*)(rowpos + N_DST);
        int* ell = (int*)full;

        hipMemsetAsync(cnt, 0, (size_t)N_DST * sizeof(int), stream);

        prep_build_kernel<<<TOTAL_BLOCKS, 256, 0, stream>>>(
            src, dst, ell, cnt, n_edges,
            reuse_idx, rowpos, n_reuse, W_self, W_neigh, wbf,
            feat_src, (unsigned int*)featbf);

        gather_bf16_kernel<<<(N_DST * 16 + 255) / 256, 256, 0, stream>>>(
            featbf, ell, cnt, (uint4*)hneigh);

        gemm_kernel<<<(N_DST + 127) / 128, 256, 0, stream>>>(
            featbf, hneigh, wbf, rowpos, full);

        epilogue_kernel<<<(ep_rows * 32 + 255) / 256, 256, 0, stream>>>(
            reuse_emb, reuse_idx, n_reuse, full, cache_idx, cache_out, n_cache);
    } else {
        // ---- fallback (r2-verified layout): ell in ws, featbf borrows d_out ----
        unsigned short* hneigh = (unsigned short*)d_ws;
        int*   ell    = (int*)((char*)d_ws + hneigh_b);
        int*   cnt    = (int*)((char*)ell + ell_b);
        int*   rowpos = cnt + N_DST;
        unsigned short* wbf = (unsigned short*)(rowpos + N_DST);
        unsigned short* featbf = (unsigned short*)full;

        hipMemsetAsync(cnt, 0, (size_t)N_DST * sizeof(int), stream);

        prep_build_kernel<<<TOTAL_BLOCKS, 256, 0, stream>>>(
            src, dst, ell, cnt, n_edges,
            reuse_idx, rowpos, n_reuse, W_self, W_neigh, wbf,
            feat_src, (unsigned int*)featbf);

        gather_bf16_kernel<<<(N_DST * 16 + 255) / 256, 256, 0, stream>>>(
            featbf, ell, cnt, (uint4*)hneigh);

        gemm_f32a_kernel<<<(N_DST + 127) / 128, 256, 0, stream>>>(
            feat_src, hneigh, wbf, rowpos, full);

        epilogue_kernel<<<(ep_rows * 32 + 255) / 256, 256, 0, stream>>>(
            reuse_emb, reuse_idx, n_reuse, full, cache_idx, cache_out, n_cache);
    }
}